// Round 1
// 588.268 us; speedup vs baseline: 1.1388x; 1.1388x over previous
//
#include <hip/hip_runtime.h>

// B=16, H=W=56, C=512, heads=8, hd=64; idx=0 -> H_sp=56, W_sp=7 -> S=392,
// 8 windows/batch, 128 windows total.  I/O dtype: float32.
#define B_    16
#define HIMG  56
#define WIMG  56
#define L_    3136
#define C_    512
#define NH_   8
#define HD_   64
#define S_    392
#define NKT   13       // key chunks of 32
#define NQT   13       // q tiles of 32 rows

typedef short short4v __attribute__((ext_vector_type(4)));
typedef short short8  __attribute__((ext_vector_type(8)));
typedef float f32x4   __attribute__((ext_vector_type(4)));
typedef float f32x16  __attribute__((ext_vector_type(16)));

__device__ __forceinline__ short f2bf(float f) {
    union { float f; unsigned int i; } x; x.f = f;
    unsigned int i = x.i;
    i += 0x7fffu + ((i >> 16) & 1u);   // RNE
    return (short)(i >> 16);
}
// window-position s (= h*7 + wsp) -> flat image index l for window column ww
__device__ __forceinline__ int l_of(int s, int ww) {
    int h = s / 7;
    int wp = s - h * 7;
    return h * WIMG + ww * 7 + wp;
}

// ---------------------------------------------------------------------------
// Kernel 1: depthwise 3x3 LePE conv (zero pad at window boundaries), fp32.
// Weights staged in LDS (transposed [k][c], stride 516 for aligned float4).
// ---------------------------------------------------------------------------
__global__ __launch_bounds__(256) void lepe_kernel(
    const float* __restrict__ vp, const float* __restrict__ cw,
    const float* __restrict__ cb, float* __restrict__ out)
{
    __shared__ __align__(16) float sW[9 * 516];   // sW[k][c], 18.6 KB

    for (int i = threadIdx.x; i < 1152; i += 256) {
        f32x4 v = *(const f32x4*)(cw + i * 4);
#pragma unroll
        for (int j = 0; j < 4; ++j) {
            int e = 4 * i + j;
            int c = e / 9;
            int k = e - 9 * c;
            sW[k * 516 + c] = v[j];
        }
    }
    __syncthreads();

    int g    = blockIdx.x * 256 + threadIdx.x;
    int c0   = (g & 127) * 4;
    int rest = g >> 7;                 // b*L + l
    int l    = rest % L_;
    int h    = l / WIMG;
    int wim  = l - h * WIMG;
    int wsp  = wim % 7;

    f32x4 acc = *(const f32x4*)(cb + c0);
    const long long base = (long long)rest * C_ + c0;
#pragma unroll
    for (int dh = -1; dh <= 1; ++dh) {
        int hh = h + dh;
        if (hh < 0 || hh >= HIMG) continue;          // image edge == window edge in h
#pragma unroll
        for (int dw = -1; dw <= 1; ++dw) {
            int wp2 = wsp + dw;                      // zero-pad at WINDOW edge in w
            if (wp2 < 0 || wp2 >= 7) continue;
            f32x4 vv = *(const f32x4*)(vp + base + (long long)(dh * WIMG + dw) * C_);
            int k = (dh + 1) * 3 + (dw + 1);
            f32x4 wv = *(const f32x4*)&sW[k * 516 + c0];
#pragma unroll
            for (int i = 0; i < 4; ++i) acc[i] += vv[i] * wv[i];
        }
    }
    *(f32x4*)(out + base) = acc;
}

// ---------------------------------------------------------------------------
// Kernel 2: window attention, one WG (8 waves, 512 thr) per (win, head).
// 32x32x16 MFMA, SWAPPED operands: S^T = mfma(K, Q) so each lane owns the
// full softmax state of ONE q-row (q = lane&31). P is packed to bf16 pairs
// in-register (v_cvt_pk_bf16_f32) and exchanged across 32-lane halves with
// shfl_xor(32); O is accumulated transposed via O^T = mfma(V, P), so the
// rescale and 1/l epilogue are lane-local. No P LDS round trip.
// LDS: sK bf16[392][72] @0 (56448 B, conflict-free A-frag reads);
//      sV bf16[64][448] with t ^= ((d>>3)&3)<<4 swizzle (57344 B,
//      conflict-free A-frag reads).  Total 113792 B. One barrier.
// ---------------------------------------------------------------------------
__global__ __launch_bounds__(512) void attn_kernel(
    const float* __restrict__ qkv, float* __restrict__ out)
{
    const int head = blockIdx.x;          // 0..7
    const int win  = blockIdx.y;          // 0..127
    const int b    = win >> 3;
    const int ww   = win & 7;

    const int tid  = threadIdx.x;
    const int wave = tid >> 6;
    const int lane = tid & 63;
    const int l31  = lane & 31;
    const int hi   = lane >> 5;

    const float* kp = qkv + (long long)B_ * L_ * C_;
    const float* vp = qkv + 2LL * (long long)B_ * L_ * C_;

    __shared__ __align__(16) short sAll[56896];   // 113792 B
    short* sK = sAll;                  // [392][72]
    short* sV = sAll + 28224;          // [64][448], t bits4..5 XOR'd by d bits3..4

    const int st_r = tid >> 4;         // 0..31
    const int st_c = (tid & 15) * 4;   // 0..60

    const long long kvbase = (long long)b * L_ * C_ + head * HD_;

    // ---- stage K (t-major bf16), once ----
#pragma unroll
    for (int p = 0; p < 13; ++p) {
        int t = p * 32 + st_r;
        if (t < S_) {
            f32x4 kv = *(const f32x4*)(kp + kvbase + (long long)l_of(t, ww) * C_ + st_c);
            short4v ks;
#pragma unroll
            for (int j = 0; j < 4; ++j) ks[j] = f2bf(kv[j]);
            *(short4v*)&sK[t * 72 + st_c] = ks;
        }
    }
    // ---- stage V (d-major bf16, swizzled), zero tail ----
#pragma unroll
    for (int p = 0; p < 14; ++p) {
        int t = p * 32 + st_r;                 // 0..447
        f32x4 vv = {0.f, 0.f, 0.f, 0.f};
        if (t < S_)
            vv = *(const f32x4*)(vp + kvbase + (long long)l_of(t, ww) * C_ + st_c);
#pragma unroll
        for (int j = 0; j < 4; ++j) {
            int d  = st_c + j;
            int sw = ((d >> 3) & 3) << 4;      // XOR t bits 4..5 (bijective in [0,448))
            sV[d * 448 + (t ^ sw)] = f2bf(vv[j]);
        }
    }
    __syncthreads();   // the only barrier

    const float SCL = 0.125f * 1.44269504088896340736f;  // hd^-0.5 * log2(e)

    for (int qt = wave; qt < NQT; qt += 8) {
        const int qrow0 = qt * 32;
        int qs = qrow0 + l31; if (qs > S_ - 1) qs = S_ - 1;
        const float* qp = qkv + (long long)b * L_ * C_
                        + (long long)l_of(qs, ww) * C_ + head * HD_ + hi * 8;
        // Q B-frag: B[n=q=l31][k=16kk+8hi+j]
        short8 bq[4];
#pragma unroll
        for (int kk = 0; kk < 4; ++kk) {
            f32x4 x0 = *(const f32x4*)(qp + kk * 16);
            f32x4 x1 = *(const f32x4*)(qp + kk * 16 + 4);
            short8 t;
#pragma unroll
            for (int j = 0; j < 4; ++j) { t[j] = f2bf(x0[j]); t[4 + j] = f2bf(x1[j]); }
            bq[kk] = t;
        }

        f32x16 Oa0, Oa1;                 // O^T[d = {0,32}+crow(r,hi)][q = l31]
#pragma unroll
        for (int r = 0; r < 16; ++r) { Oa0[r] = 0.f; Oa1[r] = 0.f; }
        float mrun = -1e30f, lrun = 0.f; // per-lane: state of q-row l31

        for (int ch = 0; ch < NKT; ++ch) {
            const int kt0 = ch * 32;
            int krow = kt0 + l31; if (krow > S_ - 1) krow = S_ - 1;   // clamp (masked)
            const short* kr = &sK[krow * 72 + hi * 8];

            // ---- S^T = K Q^T : C[m=key][n=q] ----
            f32x16 acc;
#pragma unroll
            for (int r = 0; r < 16; ++r) acc[r] = 0.f;
#pragma unroll
            for (int kk = 0; kk < 4; ++kk) {
                short8 ak = *(const short8*)(kr + kk * 16);
                acc = __builtin_amdgcn_mfma_f32_32x32x16_bf16(ak, bq[kk], acc, 0, 0, 0);
            }
            // ---- scale + tail-mask + row max (acc[r] = S[q=l31][key=kt0+crow(r,hi)]) ----
            float pm = -1e30f;
#pragma unroll
            for (int r = 0; r < 16; ++r) {
                int key = kt0 + (r & 3) + 8 * (r >> 2) + 4 * hi;
                float v = acc[r] * SCL;
                v = (key < S_) ? v : -1e30f;
                acc[r] = v;
                pm = fmaxf(pm, v);
            }
            pm = fmaxf(pm, __shfl_xor(pm, 32));
            // ---- defer-max rescale (T13, THR=8 in log2 domain) ----
            if (__any(pm > mrun + 8.f)) {
                float mnew  = fmaxf(mrun, pm);
                float alpha = exp2f(mrun - mnew);
#pragma unroll
                for (int r = 0; r < 16; ++r) { Oa0[r] *= alpha; Oa1[r] *= alpha; }
                lrun *= alpha;
                mrun = mnew;
            }
            float rs = 0.f;
#pragma unroll
            for (int r = 0; r < 16; ++r) {
                float p = exp2f(acc[r] - mrun);
                acc[r] = p;
                rs += p;
            }
            rs += __shfl_xor(rs, 32);
            lrun += rs;
            // ---- pack P to bf16 pairs: u[2a+h] = (p[4a+2h], p[4a+2h+1]) ----
            unsigned int u[8];
#pragma unroll
            for (int a = 0; a < 4; ++a)
#pragma unroll
                for (int h = 0; h < 2; ++h) {
                    unsigned int r_;
                    asm("v_cvt_pk_bf16_f32 %0, %1, %2"
                        : "=v"(r_) : "v"(acc[4 * a + 2 * h]), "v"(acc[4 * a + 2 * h + 1]));
                    u[a * 2 + h] = r_;
                }
            // ---- O^T += V^T P^T : per kkp, exchange half-held pairs across hi ----
#pragma unroll
            for (int kkp = 0; kkp < 2; ++kkp) {
                unsigned int sA0 = (unsigned int)__shfl_xor((int)u[4 * kkp + 0], 32);
                unsigned int sA1 = (unsigned int)__shfl_xor((int)u[4 * kkp + 1], 32);
                unsigned int sB0 = (unsigned int)__shfl_xor((int)u[4 * kkp + 2], 32);
                unsigned int sB1 = (unsigned int)__shfl_xor((int)u[4 * kkp + 3], 32);
                union { unsigned int w[4]; short8 s; } pb;
                pb.w[0] = hi ? sB0 : u[4 * kkp + 0];
                pb.w[1] = hi ? sB1 : u[4 * kkp + 1];
                pb.w[2] = hi ? u[4 * kkp + 2] : sA0;
                pb.w[3] = hi ? u[4 * kkp + 3] : sA1;
                const int Tb = kt0 + kkp * 16 + hi * 8;
                {
                    int d = l31;
                    short8 av = *(const short8*)&sV[d * 448 + (Tb ^ (((d >> 3) & 3) << 4))];
                    Oa0 = __builtin_amdgcn_mfma_f32_32x32x16_bf16(av, pb.s, Oa0, 0, 0, 0);
                }
                {
                    int d = 32 + l31;
                    short8 av = *(const short8*)&sV[d * 448 + (Tb ^ (((d >> 3) & 3) << 4))];
                    Oa1 = __builtin_amdgcn_mfma_f32_32x32x16_bf16(av, pb.s, Oa1, 0, 0, 0);
                }
            }
        } // chunk loop

        // ---- epilogue: lane-local 1/l, vectorized fp32 RMW onto lepe ----
        if (qrow0 + l31 < S_) {
            float inv = 1.0f / lrun;
            float* op = out + (long long)b * L_ * C_
                      + (long long)l_of(qrow0 + l31, ww) * C_ + head * HD_;
#pragma unroll
            for (int g = 0; g < 4; ++g) {       // d = 8g + 4hi + j  (Oa0 reg 4g+j)
                float* p4 = op + g * 8 + hi * 4;
                f32x4 t = *(f32x4*)p4;
#pragma unroll
                for (int j = 0; j < 4; ++j) t[j] += Oa0[4 * g + j] * inv;
                *(f32x4*)p4 = t;
            }
#pragma unroll
            for (int g = 0; g < 4; ++g) {       // d = 32 + 8g + 4hi + j
                float* p4 = op + 32 + g * 8 + hi * 4;
                f32x4 t = *(f32x4*)p4;
#pragma unroll
                for (int j = 0; j < 4; ++j) t[j] += Oa1[4 * g + j] * inv;
                *(f32x4*)p4 = t;
            }
        }
    } // q-tile loop
}

extern "C" void kernel_launch(void* const* d_in, const int* in_sizes, int n_in,
                              void* d_out, int out_size, void* d_ws, size_t ws_size,
                              hipStream_t stream) {
    (void)in_sizes; (void)n_in; (void)d_ws; (void)ws_size; (void)out_size;
    const float* qkv = (const float*)d_in[0];
    const float* cw  = (const float*)d_in[1];
    const float* cb  = (const float*)d_in[2];
    float* out = (float*)d_out;
    const float* vp = qkv + 2LL * (long long)B_ * L_ * C_;

    // lepe writes d_out; attention RMW-adds onto it (same stream => ordered).
    lepe_kernel<<<dim3((B_ * L_ * (C_ / 4)) / 256), dim3(256), 0, stream>>>(vp, cw, cb, out);
    attn_kernel<<<dim3(NH_, B_ * 8), dim3(512), 0, stream>>>(qkv, out);
}

// Round 2
// 586.780 us; speedup vs baseline: 1.1417x; 1.0025x over previous
//
#include <hip/hip_runtime.h>

// B=16, H=W=56, C=512, heads=8, hd=64; idx=0 -> H_sp=56, W_sp=7 -> S=392,
// 8 windows/batch, 128 windows total.  I/O dtype: float32.
#define B_    16
#define HIMG  56
#define WIMG  56
#define L_    3136
#define C_    512
#define NH_   8
#define HD_   64
#define S_    392
#define NKT   13       // key chunks of 32
#define NQT   13       // q tiles of 32 rows
#define NITEM 4        // (win,head) items per persistent WG: 1024 / 256

typedef short short4v __attribute__((ext_vector_type(4)));
typedef short short8  __attribute__((ext_vector_type(8)));
typedef float f32x4   __attribute__((ext_vector_type(4)));
typedef float f32x16  __attribute__((ext_vector_type(16)));

__device__ __forceinline__ short f2bf(float f) {
    union { float f; unsigned int i; } x; x.f = f;
    unsigned int i = x.i;
    i += 0x7fffu + ((i >> 16) & 1u);   // RNE
    return (short)(i >> 16);
}
// window-position s (= h*7 + wsp) -> flat image index l for window column ww
__device__ __forceinline__ int l_of(int s, int ww) {
    int h = s / 7;
    int wp = s - h * 7;
    return h * WIMG + ww * 7 + wp;
}

// ---------------------------------------------------------------------------
// Kernel 1: depthwise 3x3 LePE conv (zero pad at window boundaries), fp32.
// ---------------------------------------------------------------------------
__global__ __launch_bounds__(256) void lepe_kernel(
    const float* __restrict__ vp, const float* __restrict__ cw,
    const float* __restrict__ cb, float* __restrict__ out)
{
    __shared__ __align__(16) float sW[9 * 516];   // sW[k][c], 18.6 KB

    for (int i = threadIdx.x; i < 1152; i += 256) {
        f32x4 v = *(const f32x4*)(cw + i * 4);
#pragma unroll
        for (int j = 0; j < 4; ++j) {
            int e = 4 * i + j;
            int c = e / 9;
            int k = e - 9 * c;
            sW[k * 516 + c] = v[j];
        }
    }
    __syncthreads();

    int g    = blockIdx.x * 256 + threadIdx.x;
    int c0   = (g & 127) * 4;
    int rest = g >> 7;                 // b*L + l
    int l    = rest % L_;
    int h    = l / WIMG;
    int wim  = l - h * WIMG;
    int wsp  = wim % 7;

    f32x4 acc = *(const f32x4*)(cb + c0);
    const long long base = (long long)rest * C_ + c0;
#pragma unroll
    for (int dh = -1; dh <= 1; ++dh) {
        int hh = h + dh;
        if (hh < 0 || hh >= HIMG) continue;          // image edge == window edge in h
#pragma unroll
        for (int dw = -1; dw <= 1; ++dw) {
            int wp2 = wsp + dw;                      // zero-pad at WINDOW edge in w
            if (wp2 < 0 || wp2 >= 7) continue;
            f32x4 vv = *(const f32x4*)(vp + base + (long long)(dh * WIMG + dw) * C_);
            int k = (dh + 1) * 3 + (dw + 1);
            f32x4 wv = *(const f32x4*)&sW[k * 516 + c0];
#pragma unroll
            for (int i = 0; i < 4; ++i) acc[i] += vv[i] * wv[i];
        }
    }
    *(f32x4*)(out + base) = acc;
}

// ---------------------------------------------------------------------------
// Kernel 2: persistent window attention. 256 WGs (8 waves each); each WG
// loops over 4 (win,head) items reusing the same LDS K/V residency.
// Staging is register-batched (13 K + 14 V f32x4 loads issued before any
// convert) for max MLP, and the NEXT item's K payload is prefetched into
// registers right after the stage barrier so its HBM latency hides under
// the ~14 us compute phase.  Compute body identical to the verified
// swapped-operand 32x32 kernel: S^T = mfma(K,Q), in-register softmax,
// O^T = mfma(V,P), lane-local state, no P LDS round trip.
// LDS: sK bf16[392][72] @0; sV bf16[64][448] t-XOR-swizzled. 113792 B.
// ---------------------------------------------------------------------------
__global__ __launch_bounds__(512) void attn_kernel(
    const float* __restrict__ qkv, float* __restrict__ out)
{
    const int wg   = blockIdx.x;          // 0..255 persistent
    const int tid  = threadIdx.x;
    const int wave = tid >> 6;
    const int lane = tid & 63;
    const int l31  = lane & 31;
    const int hi   = lane >> 5;

    const float* kp = qkv + (long long)B_ * L_ * C_;
    const float* vp = qkv + 2LL * (long long)B_ * L_ * C_;

    __shared__ __align__(16) short sAll[56896];   // 113792 B
    short* sK = sAll;                  // [392][72]
    short* sV = sAll + 28224;          // [64][448], t bits4..5 XOR'd by d bits3..4

    const int st_r = tid >> 4;         // 0..31
    const int st_c = (tid & 15) * 4;   // 0..60

    f32x4 kbuf[13];                    // K payload (52 VGPR), lives across compute
    f32x4 vbuf[14];                    // V payload (56 VGPR), stage-local

    // ---- issue K loads for item 0 (cold) ----
    {
        const int id = wg;
        const int head0 = id & 7, win0 = id >> 3;
        const int b0 = win0 >> 3, ww0 = win0 & 7;
        const long long kvb = (long long)b0 * L_ * C_ + head0 * HD_;
#pragma unroll
        for (int p = 0; p < 13; ++p) {
            int t = p * 32 + st_r;
            if (t < S_)
                kbuf[p] = *(const f32x4*)(kp + kvb + (long long)l_of(t, ww0) * C_ + st_c);
        }
    }
    __builtin_amdgcn_sched_barrier(0);

    const float SCL = 0.125f * 1.44269504088896340736f;  // hd^-0.5 * log2(e)

    for (int item = 0; item < NITEM; ++item) {
        const int id   = item * 256 + wg;
        const int head = id & 7;
        const int win  = id >> 3;
        const int b    = win >> 3;
        const int ww   = win & 7;
        const long long kvbase = (long long)b * L_ * C_ + head * HD_;

        // ---- issue V loads for this item (batched) ----
#pragma unroll
        for (int p = 0; p < 14; ++p) {
            int t = p * 32 + st_r;                 // 0..447
            f32x4 vv = {0.f, 0.f, 0.f, 0.f};
            if (t < S_)
                vv = *(const f32x4*)(vp + kvbase + (long long)l_of(t, ww) * C_ + st_c);
            vbuf[p] = vv;
        }
        __builtin_amdgcn_sched_barrier(0);

        __syncthreads();   // prev item's compute done; drains in-flight loads

        // ---- write K (bf16) ----
#pragma unroll
        for (int p = 0; p < 13; ++p) {
            int t = p * 32 + st_r;
            if (t < S_) {
                short4v ks;
#pragma unroll
                for (int j = 0; j < 4; ++j) ks[j] = f2bf(kbuf[p][j]);
                *(short4v*)&sK[t * 72 + st_c] = ks;
            }
        }
        // ---- write V (bf16, d-major, swizzled) ----
#pragma unroll
        for (int p = 0; p < 14; ++p) {
            int t = p * 32 + st_r;
#pragma unroll
            for (int j = 0; j < 4; ++j) {
                int d  = st_c + j;
                int sw = ((d >> 3) & 3) << 4;      // XOR t bits 4..5 (bijective)
                sV[d * 448 + (t ^ sw)] = f2bf(vbuf[p][j]);
            }
        }
        __syncthreads();

        // ---- prefetch next item's K into registers (streams under compute) ----
        if (item < NITEM - 1) {
            const int id2 = (item + 1) * 256 + wg;
            const int head2 = id2 & 7, win2 = id2 >> 3;
            const int b2 = win2 >> 3, ww2 = win2 & 7;
            const long long kvb2 = (long long)b2 * L_ * C_ + head2 * HD_;
#pragma unroll
            for (int p = 0; p < 13; ++p) {
                int t = p * 32 + st_r;
                if (t < S_)
                    kbuf[p] = *(const f32x4*)(kp + kvb2 + (long long)l_of(t, ww2) * C_ + st_c);
            }
            __builtin_amdgcn_sched_barrier(0);
        }

        // ================= compute (verified round-1 body) =================
        for (int qt = wave; qt < NQT; qt += 8) {
            const int qrow0 = qt * 32;
            int qs = qrow0 + l31; if (qs > S_ - 1) qs = S_ - 1;
            const float* qp = qkv + (long long)b * L_ * C_
                            + (long long)l_of(qs, ww) * C_ + head * HD_ + hi * 8;
            // Q B-frag: B[n=q=l31][k=16kk+8hi+j]
            short8 bq[4];
#pragma unroll
            for (int kk = 0; kk < 4; ++kk) {
                f32x4 x0 = *(const f32x4*)(qp + kk * 16);
                f32x4 x1 = *(const f32x4*)(qp + kk * 16 + 4);
                short8 t;
#pragma unroll
                for (int j = 0; j < 4; ++j) { t[j] = f2bf(x0[j]); t[4 + j] = f2bf(x1[j]); }
                bq[kk] = t;
            }

            f32x16 Oa0, Oa1;                 // O^T[d = {0,32}+crow(r,hi)][q = l31]
#pragma unroll
            for (int r = 0; r < 16; ++r) { Oa0[r] = 0.f; Oa1[r] = 0.f; }
            float mrun = -1e30f, lrun = 0.f; // per-lane: state of q-row l31

            for (int ch = 0; ch < NKT; ++ch) {
                const int kt0 = ch * 32;
                int krow = kt0 + l31; if (krow > S_ - 1) krow = S_ - 1;  // clamp (masked)
                const short* kr = &sK[krow * 72 + hi * 8];

                // ---- S^T = K Q^T : C[m=key][n=q] ----
                f32x16 acc;
#pragma unroll
                for (int r = 0; r < 16; ++r) acc[r] = 0.f;
#pragma unroll
                for (int kk = 0; kk < 4; ++kk) {
                    short8 ak = *(const short8*)(kr + kk * 16);
                    acc = __builtin_amdgcn_mfma_f32_32x32x16_bf16(ak, bq[kk], acc, 0, 0, 0);
                }
                // ---- scale + tail-mask + row max ----
                float pm = -1e30f;
#pragma unroll
                for (int r = 0; r < 16; ++r) {
                    int key = kt0 + (r & 3) + 8 * (r >> 2) + 4 * hi;
                    float v = acc[r] * SCL;
                    v = (key < S_) ? v : -1e30f;
                    acc[r] = v;
                    pm = fmaxf(pm, v);
                }
                pm = fmaxf(pm, __shfl_xor(pm, 32));
                // ---- defer-max rescale (THR=8 in log2 domain) ----
                if (__any(pm > mrun + 8.f)) {
                    float mnew  = fmaxf(mrun, pm);
                    float alpha = exp2f(mrun - mnew);
#pragma unroll
                    for (int r = 0; r < 16; ++r) { Oa0[r] *= alpha; Oa1[r] *= alpha; }
                    lrun *= alpha;
                    mrun = mnew;
                }
                float rs = 0.f;
#pragma unroll
                for (int r = 0; r < 16; ++r) {
                    float p = exp2f(acc[r] - mrun);
                    acc[r] = p;
                    rs += p;
                }
                rs += __shfl_xor(rs, 32);
                lrun += rs;
                // ---- pack P to bf16 pairs ----
                unsigned int u[8];
#pragma unroll
                for (int a = 0; a < 4; ++a)
#pragma unroll
                    for (int h = 0; h < 2; ++h) {
                        unsigned int r_;
                        asm("v_cvt_pk_bf16_f32 %0, %1, %2"
                            : "=v"(r_) : "v"(acc[4 * a + 2 * h]), "v"(acc[4 * a + 2 * h + 1]));
                        u[a * 2 + h] = r_;
                    }
                // ---- O^T += V^T P^T : exchange half-held pairs across hi ----
#pragma unroll
                for (int kkp = 0; kkp < 2; ++kkp) {
                    unsigned int sA0 = (unsigned int)__shfl_xor((int)u[4 * kkp + 0], 32);
                    unsigned int sA1 = (unsigned int)__shfl_xor((int)u[4 * kkp + 1], 32);
                    unsigned int sB0 = (unsigned int)__shfl_xor((int)u[4 * kkp + 2], 32);
                    unsigned int sB1 = (unsigned int)__shfl_xor((int)u[4 * kkp + 3], 32);
                    union { unsigned int w[4]; short8 s; } pb;
                    pb.w[0] = hi ? sB0 : u[4 * kkp + 0];
                    pb.w[1] = hi ? sB1 : u[4 * kkp + 1];
                    pb.w[2] = hi ? u[4 * kkp + 2] : sA0;
                    pb.w[3] = hi ? u[4 * kkp + 3] : sA1;
                    const int Tb = kt0 + kkp * 16 + hi * 8;
                    {
                        int d = l31;
                        short8 av = *(const short8*)&sV[d * 448 + (Tb ^ (((d >> 3) & 3) << 4))];
                        Oa0 = __builtin_amdgcn_mfma_f32_32x32x16_bf16(av, pb.s, Oa0, 0, 0, 0);
                    }
                    {
                        int d = 32 + l31;
                        short8 av = *(const short8*)&sV[d * 448 + (Tb ^ (((d >> 3) & 3) << 4))];
                        Oa1 = __builtin_amdgcn_mfma_f32_32x32x16_bf16(av, pb.s, Oa1, 0, 0, 0);
                    }
                }
            } // chunk loop

            // ---- epilogue: lane-local 1/l, vectorized fp32 RMW onto lepe ----
            if (qrow0 + l31 < S_) {
                float inv = 1.0f / lrun;
                float* op = out + (long long)b * L_ * C_
                          + (long long)l_of(qrow0 + l31, ww) * C_ + head * HD_;
#pragma unroll
                for (int g = 0; g < 4; ++g) {       // d = 8g + 4hi + j
                    float* p4 = op + g * 8 + hi * 4;
                    f32x4 t = *(f32x4*)p4;
#pragma unroll
                    for (int j = 0; j < 4; ++j) t[j] += Oa0[4 * g + j] * inv;
                    *(f32x4*)p4 = t;
                }
#pragma unroll
                for (int g = 0; g < 4; ++g) {       // d = 32 + 8g + 4hi + j
                    float* p4 = op + 32 + g * 8 + hi * 4;
                    f32x4 t = *(f32x4*)p4;
#pragma unroll
                    for (int j = 0; j < 4; ++j) t[j] += Oa1[4 * g + j] * inv;
                    *(f32x4*)p4 = t;
                }
            }
        } // q-tile loop
    } // item loop
}

extern "C" void kernel_launch(void* const* d_in, const int* in_sizes, int n_in,
                              void* d_out, int out_size, void* d_ws, size_t ws_size,
                              hipStream_t stream) {
    (void)in_sizes; (void)n_in; (void)d_ws; (void)ws_size; (void)out_size;
    const float* qkv = (const float*)d_in[0];
    const float* cw  = (const float*)d_in[1];
    const float* cb  = (const float*)d_in[2];
    float* out = (float*)d_out;
    const float* vp = qkv + 2LL * (long long)B_ * L_ * C_;

    // lepe writes d_out; attention RMW-adds onto it (same stream => ordered).
    lepe_kernel<<<dim3((B_ * L_ * (C_ / 4)) / 256), dim3(256), 0, stream>>>(vp, cw, cb, out);
    attn_kernel<<<dim3(256), dim3(512), 0, stream>>>(qkv, out);
}

// Round 5
// 569.571 us; speedup vs baseline: 1.1762x; 1.0302x over previous
//
#include <hip/hip_runtime.h>

// B=16, H=W=56, C=512, heads=8, hd=64; idx=0 -> H_sp=56, W_sp=7 -> S=392,
// 8 windows/batch, 128 windows total.  I/O dtype: float32.
#define B_    16
#define HIMG  56
#define WIMG  56
#define L_    3136
#define C_    512
#define NH_   8
#define HD_   64
#define S_    392
#define NKT   13       // key chunks of 32
#define NQT   13       // q tiles of 32 rows

typedef short short4v __attribute__((ext_vector_type(4)));
typedef short short8  __attribute__((ext_vector_type(8)));
typedef float f32x4   __attribute__((ext_vector_type(4)));
typedef float f32x16  __attribute__((ext_vector_type(16)));

__device__ __forceinline__ short f2bf(float f) {
    union { float f; unsigned int i; } x; x.f = f;
    unsigned int i = x.i;
    i += 0x7fffu + ((i >> 16) & 1u);   // RNE
    return (short)(i >> 16);
}
// window-position s (= h*7 + wsp) -> flat image index l for window column ww
__device__ __forceinline__ int l_of(int s, int ww) {
    int h = s / 7;
    int wp = s - h * 7;
    return h * WIMG + ww * 7 + wp;
}

// ---------------------------------------------------------------------------
// Kernel 1: depthwise 3x3 LePE conv (zero pad at window boundaries), fp32.
// ---------------------------------------------------------------------------
__global__ __launch_bounds__(256) void lepe_kernel(
    const float* __restrict__ vp, const float* __restrict__ cw,
    const float* __restrict__ cb, float* __restrict__ out)
{
    __shared__ __align__(16) float sW[9 * 516];   // sW[k][c], 18.6 KB

    for (int i = threadIdx.x; i < 1152; i += 256) {
        f32x4 v = *(const f32x4*)(cw + i * 4);
#pragma unroll
        for (int j = 0; j < 4; ++j) {
            int e = 4 * i + j;
            int c = e / 9;
            int k = e - 9 * c;
            sW[k * 516 + c] = v[j];
        }
    }
    __syncthreads();

    int g    = blockIdx.x * 256 + threadIdx.x;
    int c0   = (g & 127) * 4;
    int rest = g >> 7;                 // b*L + l
    int l    = rest % L_;
    int h    = l / WIMG;
    int wim  = l - h * WIMG;
    int wsp  = wim % 7;

    f32x4 acc = *(const f32x4*)(cb + c0);
    const long long base = (long long)rest * C_ + c0;
#pragma unroll
    for (int dh = -1; dh <= 1; ++dh) {
        int hh = h + dh;
        if (hh < 0 || hh >= HIMG) continue;          // image edge == window edge in h
#pragma unroll
        for (int dw = -1; dw <= 1; ++dw) {
            int wp2 = wsp + dw;                      // zero-pad at WINDOW edge in w
            if (wp2 < 0 || wp2 >= 7) continue;
            f32x4 vv = *(const f32x4*)(vp + base + (long long)(dh * WIMG + dw) * C_);
            int k = (dh + 1) * 3 + (dw + 1);
            f32x4 wv = *(const f32x4*)&sW[k * 516 + c0];
#pragma unroll
            for (int i = 0; i < 4; ++i) acc[i] += vv[i] * wv[i];
        }
    }
    *(f32x4*)(out + base) = acc;
}

// ---------------------------------------------------------------------------
// Kernel 2: window attention, one WG of SIXTEEN waves (1024 thr) per
// (win,head).  vs the verified 512-thr version, ONLY the wave count and
// staging indexing change: 4 waves/SIMD (was 2) for latency hiding, and
// the 13 q-tiles fit in ONE per-wave round (critical path halves).
// Compute body is VERBATIM the round-1/2-verified code: S^T = mfma(K,Q),
// online softmax w/ defer-max, cvt_pk pack, shfl_xor+select half-exchange,
// O^T = mfma(V,P), lane-local state, no P LDS round trip.
// LDS: sK bf16[392][72] @0; sV bf16[64][448] t-XOR-swizzled. 113792 B.
// ---------------------------------------------------------------------------
__global__ __launch_bounds__(1024) void attn_kernel(
    const float* __restrict__ qkv, float* __restrict__ out)
{
    const int head = blockIdx.x;          // 0..7
    const int win  = blockIdx.y;          // 0..127
    const int b    = win >> 3;
    const int ww   = win & 7;

    const int tid  = threadIdx.x;
    const int wave = tid >> 6;            // 0..15
    const int lane = tid & 63;
    const int l31  = lane & 31;
    const int hi   = lane >> 5;

    const float* kp = qkv + (long long)B_ * L_ * C_;
    const float* vp = qkv + 2LL * (long long)B_ * L_ * C_;

    __shared__ __align__(16) short sAll[56896];   // 113792 B
    short* sK = sAll;                  // [392][72]
    short* sV = sAll + 28224;          // [64][448], t bits4..5 XOR'd by d bits3..4

    const int st_r = tid >> 4;         // 0..63
    const int st_c = (tid & 15) * 4;   // 0..60

    const long long kvbase = (long long)b * L_ * C_ + head * HD_;

    // ---- stage K+V: batch loads into registers, then convert+write ----
    f32x4 kbuf[7], vbuf[7];
#pragma unroll
    for (int p = 0; p < 7; ++p) {
        int t = p * 64 + st_r;
        if (t < S_)
            kbuf[p] = *(const f32x4*)(kp + kvbase + (long long)l_of(t, ww) * C_ + st_c);
    }
#pragma unroll
    for (int p = 0; p < 7; ++p) {
        int t = p * 64 + st_r;                 // 0..447
        f32x4 vv = {0.f, 0.f, 0.f, 0.f};
        if (t < S_)
            vv = *(const f32x4*)(vp + kvbase + (long long)l_of(t, ww) * C_ + st_c);
        vbuf[p] = vv;
    }
#pragma unroll
    for (int p = 0; p < 7; ++p) {
        int t = p * 64 + st_r;
        if (t < S_) {
            short4v ks;
#pragma unroll
            for (int j = 0; j < 4; ++j) ks[j] = f2bf(kbuf[p][j]);
            *(short4v*)&sK[t * 72 + st_c] = ks;
        }
    }
#pragma unroll
    for (int p = 0; p < 7; ++p) {
        int t = p * 64 + st_r;
#pragma unroll
        for (int j = 0; j < 4; ++j) {
            int d  = st_c + j;
            int sw = ((d >> 3) & 3) << 4;      // XOR t bits 4..5 (bijective)
            sV[d * 448 + (t ^ sw)] = f2bf(vbuf[p][j]);
        }
    }
    __syncthreads();   // the only barrier

    const float SCL = 0.125f * 1.44269504088896340736f;  // hd^-0.5 * log2(e)

    for (int qt = wave; qt < NQT; qt += 16) {
        const int qrow0 = qt * 32;
        int qs = qrow0 + l31; if (qs > S_ - 1) qs = S_ - 1;
        const float* qp = qkv + (long long)b * L_ * C_
                        + (long long)l_of(qs, ww) * C_ + head * HD_ + hi * 8;
        // Q B-frag: B[n=q=l31][k=16kk+8hi+j]
        short8 bq[4];
#pragma unroll
        for (int kk = 0; kk < 4; ++kk) {
            f32x4 x0 = *(const f32x4*)(qp + kk * 16);
            f32x4 x1 = *(const f32x4*)(qp + kk * 16 + 4);
            short8 t;
#pragma unroll
            for (int j = 0; j < 4; ++j) { t[j] = f2bf(x0[j]); t[4 + j] = f2bf(x1[j]); }
            bq[kk] = t;
        }

        f32x16 Oa0, Oa1;                 // O^T[d = {0,32}+crow(r,hi)][q = l31]
#pragma unroll
        for (int r = 0; r < 16; ++r) { Oa0[r] = 0.f; Oa1[r] = 0.f; }
        float mrun = -1e30f, lrun = 0.f; // per-lane: state of q-row l31

        for (int ch = 0; ch < NKT; ++ch) {
            const int kt0 = ch * 32;
            int krow = kt0 + l31; if (krow > S_ - 1) krow = S_ - 1;   // clamp (masked)
            const short* kr = &sK[krow * 72 + hi * 8];

            // ---- S^T = K Q^T : C[m=key][n=q] ----
            f32x16 acc;
#pragma unroll
            for (int r = 0; r < 16; ++r) acc[r] = 0.f;
#pragma unroll
            for (int kk = 0; kk < 4; ++kk) {
                short8 ak = *(const short8*)(kr + kk * 16);
                acc = __builtin_amdgcn_mfma_f32_32x32x16_bf16(ak, bq[kk], acc, 0, 0, 0);
            }
            // ---- scale + tail-mask + row max ----
            float pm = -1e30f;
#pragma unroll
            for (int r = 0; r < 16; ++r) {
                int key = kt0 + (r & 3) + 8 * (r >> 2) + 4 * hi;
                float v = acc[r] * SCL;
                v = (key < S_) ? v : -1e30f;
                acc[r] = v;
                pm = fmaxf(pm, v);
            }
            pm = fmaxf(pm, __shfl_xor(pm, 32));
            // ---- defer-max rescale (THR=8 in log2 domain) ----
            if (__any(pm > mrun + 8.f)) {
                float mnew  = fmaxf(mrun, pm);
                float alpha = exp2f(mrun - mnew);
#pragma unroll
                for (int r = 0; r < 16; ++r) { Oa0[r] *= alpha; Oa1[r] *= alpha; }
                lrun *= alpha;
                mrun = mnew;
            }
            float rs = 0.f;
#pragma unroll
            for (int r = 0; r < 16; ++r) {
                float p = exp2f(acc[r] - mrun);
                acc[r] = p;
                rs += p;
            }
            rs += __shfl_xor(rs, 32);
            lrun += rs;
            // ---- pack P to bf16 pairs: u[2a+h] = (p[4a+2h], p[4a+2h+1]) ----
            unsigned int u[8];
#pragma unroll
            for (int a = 0; a < 4; ++a)
#pragma unroll
                for (int h = 0; h < 2; ++h) {
                    unsigned int r_;
                    asm("v_cvt_pk_bf16_f32 %0, %1, %2"
                        : "=v"(r_) : "v"(acc[4 * a + 2 * h]), "v"(acc[4 * a + 2 * h + 1]));
                    u[a * 2 + h] = r_;
                }
            // ---- O^T += V^T P^T : exchange half-held pairs across hi ----
#pragma unroll
            for (int kkp = 0; kkp < 2; ++kkp) {
                unsigned int sA0 = (unsigned int)__shfl_xor((int)u[4 * kkp + 0], 32);
                unsigned int sA1 = (unsigned int)__shfl_xor((int)u[4 * kkp + 1], 32);
                unsigned int sB0 = (unsigned int)__shfl_xor((int)u[4 * kkp + 2], 32);
                unsigned int sB1 = (unsigned int)__shfl_xor((int)u[4 * kkp + 3], 32);
                union { unsigned int w[4]; short8 s; } pb;
                pb.w[0] = hi ? sB0 : u[4 * kkp + 0];
                pb.w[1] = hi ? sB1 : u[4 * kkp + 1];
                pb.w[2] = hi ? u[4 * kkp + 2] : sA0;
                pb.w[3] = hi ? u[4 * kkp + 3] : sA1;
                const int Tb = kt0 + kkp * 16 + hi * 8;
                {
                    int d = l31;
                    short8 av = *(const short8*)&sV[d * 448 + (Tb ^ (((d >> 3) & 3) << 4))];
                    Oa0 = __builtin_amdgcn_mfma_f32_32x32x16_bf16(av, pb.s, Oa0, 0, 0, 0);
                }
                {
                    int d = 32 + l31;
                    short8 av = *(const short8*)&sV[d * 448 + (Tb ^ (((d >> 3) & 3) << 4))];
                    Oa1 = __builtin_amdgcn_mfma_f32_32x32x16_bf16(av, pb.s, Oa1, 0, 0, 0);
                }
            }
        } // chunk loop

        // ---- epilogue: lane-local 1/l, vectorized fp32 RMW onto lepe ----
        if (qrow0 + l31 < S_) {
            float inv = 1.0f / lrun;
            float* op = out + (long long)b * L_ * C_
                      + (long long)l_of(qrow0 + l31, ww) * C_ + head * HD_;
#pragma unroll
            for (int g = 0; g < 4; ++g) {       // d = 8g + 4hi + j
                float* p4 = op + g * 8 + hi * 4;
                f32x4 t = *(f32x4*)p4;
#pragma unroll
                for (int j = 0; j < 4; ++j) t[j] += Oa0[4 * g + j] * inv;
                *(f32x4*)p4 = t;
            }
#pragma unroll
            for (int g = 0; g < 4; ++g) {       // d = 32 + 8g + 4hi + j
                float* p4 = op + 32 + g * 8 + hi * 4;
                f32x4 t = *(f32x4*)p4;
#pragma unroll
                for (int j = 0; j < 4; ++j) t[j] += Oa1[4 * g + j] * inv;
                *(f32x4*)p4 = t;
            }
        }
    } // q-tile loop
}

extern "C" void kernel_launch(void* const* d_in, const int* in_sizes, int n_in,
                              void* d_out, int out_size, void* d_ws, size_t ws_size,
                              hipStream_t stream) {
    (void)in_sizes; (void)n_in; (void)d_ws; (void)ws_size; (void)out_size;
    const float* qkv = (const float*)d_in[0];
    const float* cw  = (const float*)d_in[1];
    const float* cb  = (const float*)d_in[2];
    float* out = (float*)d_out;
    const float* vp = qkv + 2LL * (long long)B_ * L_ * C_;

    // lepe writes d_out; attention RMW-adds onto it (same stream => ordered).
    lepe_kernel<<<dim3((B_ * L_ * (C_ / 4)) / 256), dim3(256), 0, stream>>>(vp, cw, cb, out);
    attn_kernel<<<dim3(NH_, B_ * 8), dim3(1024), 0, stream>>>(qkv, out);
}